// Round 2
// baseline (192.218 us; speedup 1.0000x reference)
//
#include <hip/hip_runtime.h>

// Problem: B=32, GS=1024, PARAM=64, KEEPCONST=16, ITERATIONS=10, K_DIV=16.
// All tensors FLOAT32 (per reference dtypes; harness passes fp32 buffers).
// Closed form of the 10-iteration shift recurrence:
//   out[row, j] = f^q(val[row, j&15]),  q = j>>4,  f(x) = clip(x*s, -1, 1),
//   s = sum(mat[row, :]) / 16.
// Valid because q <= 3 <= ITERATIONS and cols 0..15 are pinned constants.

__global__ __launch_bounds__(256) void gltrivmlp_kernel(
    const float* __restrict__ mat,   // [nrows, 1024] f32
    const float* __restrict__ val,   // [nrows, 64]   f32
    float* __restrict__ out,         // [nrows, 64]   f32
    int nrows)
{
    const int gwave = (int)((blockIdx.x * (unsigned)blockDim.x + threadIdx.x) >> 6);
    const int lane  = (int)(threadIdx.x & 63u);
    if (gwave >= nrows) return;

    // ---- row sum of mat: 1024 f32, 16 per lane via 4 coalesced float4 loads ----
    const float* row = mat + (size_t)gwave * 1024;
    float sum = 0.f;
#pragma unroll
    for (int h = 0; h < 4; ++h) {
        // wave reads a contiguous 1 KiB segment: lane i -> floats [h*256 + i*4, +4)
        float4 v = *(const float4*)(row + h * 256 + lane * 4);
        sum += v.x + v.y + v.z + v.w;
    }
    // ---- 64-lane butterfly reduce ----
#pragma unroll
    for (int off = 32; off >= 1; off >>= 1)
        sum += __shfl_xor(sum, off, 64);

    const float s = sum * (1.0f / 16.0f);

    // ---- epilogue: lane j emits output column j ----
    const float* vrow = val + (size_t)gwave * 64;
    float x = vrow[lane & 15];     // cols 0..15 broadcast within wave
    const int q = lane >> 4;
    if (q >= 1) x = fminf(fmaxf(x * s, -1.f), 1.f);
    if (q >= 2) x = fminf(fmaxf(x * s, -1.f), 1.f);
    if (q >= 3) x = fminf(fmaxf(x * s, -1.f), 1.f);

    out[(size_t)gwave * 64 + lane] = x;
}

extern "C" void kernel_launch(void* const* d_in, const int* in_sizes, int n_in,
                              void* d_out, int out_size, void* d_ws, size_t ws_size,
                              hipStream_t stream) {
    (void)n_in; (void)d_ws; (void)ws_size; (void)out_size;
    const float* mat = (const float*)d_in[0];
    const float* val = (const float*)d_in[1];
    float* out = (float*)d_out;

    const int nrows = in_sizes[0] / 1024;          // 32*1024 = 32768 rows
    const int waves_per_block = 256 / 64;          // 4 rows per block
    const int grid = (nrows + waves_per_block - 1) / waves_per_block;

    gltrivmlp_kernel<<<grid, 256, 0, stream>>>(mat, val, out, nrows);
}